// Round 1
// 495.795 us; speedup vs baseline: 1.0636x; 1.0636x over previous
//
#include <hip/hip_runtime.h>
#include <hip/hip_bf16.h>

#define C_ 256
#define N_ 4096
#define CN (C_*N_)
#define EPSF 1e-5f
#define NS_ITERS 6
#define KSPLIT 16  // split-K for MFMA cov partials
#define LSTR 40   // LDS row stride in ushort: 80 B, 16B-aligned, 2-way banks (free)

typedef short bf16x8 __attribute__((ext_vector_type(8)));
typedef float f32x4 __attribute__((ext_vector_type(4)));

__device__ __forceinline__ int refl(int t) {
  return t < 0 ? -t : (t > 63 ? 126 - t : t);
}

__device__ __forceinline__ unsigned short f2bf(float x) {
  unsigned u = __float_as_uint(x);
  unsigned r = (u + 0x7FFFu + ((u >> 16) & 1u)) >> 16;
  return (unsigned short)r;
}
__device__ __forceinline__ float bf2f(unsigned short h) {
  return __uint_as_float((unsigned)h << 16);
}

__device__ __forceinline__ void fma16(float acc[4][4], float a0, float a1, float a2, float a3, float4 b) {
  acc[0][0] += a0*b.x; acc[0][1] += a0*b.y; acc[0][2] += a0*b.z; acc[0][3] += a0*b.w;
  acc[1][0] += a1*b.x; acc[1][1] += a1*b.y; acc[1][2] += a1*b.z; acc[1][3] += a1*b.w;
  acc[2][0] += a2*b.x; acc[2][1] += a2*b.y; acc[2][2] += a2*b.z; acc[2][3] += a2*b.w;
  acc[3][0] += a3*b.x; acc[3][1] += a3*b.y; acc[3][2] += a3*b.z; acc[3][3] += a3*b.w;
}

// ---------------- means ----------------
__global__ __launch_bounds__(256) void k_mean(const float* content, const float* style,
                                              float* means) {
  int c = blockIdx.x, m = blockIdx.y, t = threadIdx.x;
  const float* x = (m < 2 ? content : style) + (size_t)(m & 1) * CN + (size_t)c * N_;
  float s = 0.f;
  for (int i = t; i < N_; i += 256) s += x[i];
  __shared__ float red[256];
  red[t] = s; __syncthreads();
  for (int off = 128; off > 0; off >>= 1) { if (t < off) red[t] += red[t + off]; __syncthreads(); }
  if (t == 0) means[m * C_ + c] = red[0] * (1.f / N_);
}

// ---------------- 3-way bf16 split of raw content/style for MFMA cov ----------------
// [m][plane][c][n], n contiguous (same layout as input rows -> no transpose needed;
// cov = X·X^T reads rows of X for BOTH operands).
__global__ __launch_bounds__(256) void k_splitcov(const float* content, const float* style,
                                                  unsigned short* sp) {
  int m = blockIdx.y;
  const float* x = (m < 2 ? content : style) + (size_t)(m & 1) * CN;
  size_t base = (size_t)m * 3 * (size_t)CN;
  size_t i = ((size_t)blockIdx.x * 256 + threadIdx.x) * 4;
  float4 v = *(const float4*)&x[i];
  float vv[4] = {v.x, v.y, v.z, v.w};
  unsigned short h[4], md[4], lo[4];
#pragma unroll
  for (int j = 0; j < 4; j++) {
    unsigned short hh = f2bf(vv[j]);
    float r1 = vv[j] - bf2f(hh);
    unsigned short mm = f2bf(r1);
    float r2 = r1 - bf2f(mm);
    h[j] = hh; md[j] = mm; lo[j] = f2bf(r2);
  }
  *(ushort4*)&sp[base + i]        = make_ushort4(h[0], h[1], h[2], h[3]);
  *(ushort4*)&sp[base + CN + i]   = make_ushort4(md[0], md[1], md[2], md[3]);
  *(ushort4*)&sp[base + 2*CN + i] = make_ushort4(lo[0], lo[1], lo[2], lo[3]);
}

// ---------------- covariance raw sums via 6-term bf16 MFMA, split-K ----------------
// Same structure as k_gram: 128x128 tile, 8 waves (wv rows of 32, wu cols of 64),
// 6 x mfma_f32_16x16x32_bf16 per fragment (hh+hm+mh+hl+lh+mm -> fp32-accurate sums).
// Grid: (KSPLIT, 4 tiles, 4 m) = 256 blocks. A rows = output rows, B rows = output cols
// of the SAME matrix (both [c][n], k contiguous).
__global__ __launch_bounds__(512) void k_covmm(const unsigned short* sp, float* covp) {
  __shared__ unsigned short sm[6*128*LSTR];
  const int P = 128*LSTR;
  int t = threadIdx.x;
  int kc = blockIdx.x, m = blockIdx.z;
  int ti = blockIdx.y >> 1, tj = blockIdx.y & 1;
  const unsigned short* Xh = sp + (size_t)m * 3 * (size_t)CN;
  const unsigned short* Xm = Xh + CN;
  const unsigned short* Xl = Xh + 2*(size_t)CN;
  int v0 = ti * 128, u0 = tj * 128;
  int wave = t >> 6, lane = t & 63;
  int wv = wave >> 1, wu = wave & 1;
  int lx16 = lane & 15, quad = lane >> 4;
  int srow = t >> 2, sseg = (t & 3) * 8;   // 512 thr = 128 rows x 4 segs of 8 ushort
  f32x4 acc[2][4];
#pragma unroll
  for (int i = 0; i < 2; i++)
#pragma unroll
    for (int j = 0; j < 4; j++) acc[i][j] = (f32x4){0.f, 0.f, 0.f, 0.f};

  int kbeg = kc * (N_ / KSPLIT), kend = kbeg + (N_ / KSPLIT);
  for (int k0 = kbeg; k0 < kend; k0 += 32) {
    __syncthreads();
    {
      size_t goA = (size_t)(v0 + srow) * N_ + k0 + sseg;
      size_t goB = (size_t)(u0 + srow) * N_ + k0 + sseg;
      int lo_ = srow * LSTR + sseg;
      *(float4*)&sm[0*P + lo_] = *(const float4*)&Xh[goA];
      *(float4*)&sm[1*P + lo_] = *(const float4*)&Xm[goA];
      *(float4*)&sm[2*P + lo_] = *(const float4*)&Xl[goA];
      *(float4*)&sm[3*P + lo_] = *(const float4*)&Xh[goB];
      *(float4*)&sm[4*P + lo_] = *(const float4*)&Xm[goB];
      *(float4*)&sm[5*P + lo_] = *(const float4*)&Xl[goB];
    }
    __syncthreads();
#pragma unroll
    for (int mt = 0; mt < 2; mt++) {
      int arow = (wv*32 + mt*16 + lx16)*LSTR + quad*8;
      bf16x8 ah = *(const bf16x8*)&sm[0*P + arow];
      bf16x8 am = *(const bf16x8*)&sm[1*P + arow];
      bf16x8 al = *(const bf16x8*)&sm[2*P + arow];
#pragma unroll
      for (int nt = 0; nt < 4; nt++) {
        int brow = (wu*64 + nt*16 + lx16)*LSTR + quad*8;
        bf16x8 bh = *(const bf16x8*)&sm[3*P + brow];
        bf16x8 bm = *(const bf16x8*)&sm[4*P + brow];
        bf16x8 bl = *(const bf16x8*)&sm[5*P + brow];
        f32x4 a = acc[mt][nt];
        a = __builtin_amdgcn_mfma_f32_16x16x32_bf16(ah, bh, a, 0, 0, 0);
        a = __builtin_amdgcn_mfma_f32_16x16x32_bf16(ah, bm, a, 0, 0, 0);
        a = __builtin_amdgcn_mfma_f32_16x16x32_bf16(am, bh, a, 0, 0, 0);
        a = __builtin_amdgcn_mfma_f32_16x16x32_bf16(ah, bl, a, 0, 0, 0);
        a = __builtin_amdgcn_mfma_f32_16x16x32_bf16(al, bh, a, 0, 0, 0);
        a = __builtin_amdgcn_mfma_f32_16x16x32_bf16(am, bm, a, 0, 0, 0);
        acc[mt][nt] = a;
      }
    }
  }
  // C/D: col=lane&15, row=quad*4+i (m89/m91)
  float* O = covp + ((size_t)kc*4 + m) * 65536;
#pragma unroll
  for (int mt = 0; mt < 2; mt++)
#pragma unroll
    for (int nt = 0; nt < 4; nt++)
#pragma unroll
      for (int i = 0; i < 4; i++)
        O[(size_t)(v0 + wv*32 + mt*16 + quad*4 + i)*C_ + (u0 + wu*64 + nt*16 + lx16)] =
            acc[mt][nt][i];
}

// ---------------- trace from partials -> cnrm = (tr/256)*1.3 ----------------
__global__ __launch_bounds__(256) void k_trace2(const float* covp, const float* means,
                                                float* cnrm) {
  int m = blockIdx.x, t = threadIdx.x;
  float s = 0.f;
#pragma unroll
  for (int kc = 0; kc < KSPLIT; kc++)
    s += covp[((size_t)kc*4 + m)*65536 + (size_t)t*257];
  float mi = means[m*C_ + t];
  float d = (s - (float)N_*mi*mi) * (1.f/(float)(N_-1));
  __shared__ float red[256];
  red[t] = d; __syncthreads();
  for (int off = 128; off > 0; off >>= 1) { if (t < off) red[t] += red[t + off]; __syncthreads(); }
  if (!t) cnrm[m] = red[0] * (1.3f/256.f);
}

// ---------------- merged covred + nsinit ----------------
__global__ __launch_bounds__(256) void k_covred_init(const float* covp, const float* means,
                                                     const float* cnrm, float* Y, float* Z) {
  int i = blockIdx.x, m = blockIdx.y, j = threadIdx.x;
  float s = 0.f;
#pragma unroll
  for (int kc = 0; kc < KSPLIT; kc++)
    s += covp[((size_t)kc*4 + m)*65536 + (size_t)i*C_ + j];
  float mi = means[m*C_ + i], mj = means[m*C_ + j];
  float cv = (s - (float)N_*mi*mj) * (1.f/(float)(N_-1));
  size_t o = (size_t)m*65536 + (size_t)i*C_ + j;
  Y[o] = cv / cnrm[m];
  Z[o] = (i == j) ? 1.f : 0.f;
}

// ---------------- NS phase A: T = 3I - Z*Y ----------------
__global__ __launch_bounds__(256) void k_nsA(const float* Zin, const float* Yin, float* T) {
  int m = blockIdx.y;
  const float* A = Zin + (size_t)m*65536;
  const float* B = Yin + (size_t)m*65536;
  float* O = T + (size_t)m*65536;
  __shared__ float As[32][33], Bs[32][33];
  int t = threadIdx.x, tx = t & 15, ty = t >> 4;
  int m0 = (blockIdx.x >> 3) * 32, n0 = (blockIdx.x & 7) * 32;
  float acc[2][2] = {};
  for (int k0 = 0; k0 < 256; k0 += 32) {
#pragma unroll
    for (int l = 0; l < 4; l++) {
      int e = t + l * 256;
      int rr = e >> 5, cc = e & 31;
      As[rr][cc] = A[(size_t)(m0+rr)*256 + k0+cc];
      Bs[rr][cc] = B[(size_t)(k0+rr)*256 + n0+cc];
    }
    __syncthreads();
#pragma unroll
    for (int kk = 0; kk < 32; kk++) {
      float a0 = As[ty*2][kk], a1 = As[ty*2+1][kk];
      float b0 = Bs[kk][tx*2], b1 = Bs[kk][tx*2+1];
      acc[0][0] += a0*b0; acc[0][1] += a0*b1; acc[1][0] += a1*b0; acc[1][1] += a1*b1;
    }
    __syncthreads();
  }
#pragma unroll
  for (int a = 0; a < 2; a++)
#pragma unroll
    for (int b = 0; b < 2; b++) {
      int r = m0 + ty*2 + a, c = n0 + tx*2 + b;
      O[(size_t)r*256 + c] = (r == c) ? 3.f - acc[a][b] : -acc[a][b];
    }
}

// ---------------- NS phase B ----------------
__global__ __launch_bounds__(256) void k_nsB(const float* Yin, const float* Zin, const float* T,
                                             float* Yout, float* Zout) {
  int m = blockIdx.y, z = blockIdx.z;
  const float* A = (z == 0 ? Yin : T) + (size_t)m*65536;
  const float* B = (z == 0 ? T : Zin) + (size_t)m*65536;
  float* O = (z == 0 ? Yout : Zout) + (size_t)m*65536;
  __shared__ float As[32][33], Bs[32][33];
  int t = threadIdx.x, tx = t & 15, ty = t >> 4;
  int m0 = (blockIdx.x >> 3) * 32, n0 = (blockIdx.x & 7) * 32;
  float acc[2][2] = {};
  for (int k0 = 0; k0 < 256; k0 += 32) {
#pragma unroll
    for (int l = 0; l < 4; l++) {
      int e = t + l * 256;
      int rr = e >> 5, cc = e & 31;
      As[rr][cc] = A[(size_t)(m0+rr)*256 + k0+cc];
      Bs[rr][cc] = B[(size_t)(k0+rr)*256 + n0+cc];
    }
    __syncthreads();
#pragma unroll
    for (int kk = 0; kk < 32; kk++) {
      float a0 = As[ty*2][kk], a1 = As[ty*2+1][kk];
      float b0 = Bs[kk][tx*2], b1 = Bs[kk][tx*2+1];
      acc[0][0] += a0*b0; acc[0][1] += a0*b1; acc[1][0] += a1*b0; acc[1][1] += a1*b1;
    }
    __syncthreads();
  }
#pragma unroll
  for (int a = 0; a < 2; a++)
#pragma unroll
    for (int b = 0; b < 2; b++)
      O[(size_t)(m0+ty*2+a)*256 + n0+tx*2+b] = 0.5f * acc[a][b];
}

// ---------------- whiten ----------------
__global__ __launch_bounds__(256) void k_whiten(const float* content, const float* style,
                                                const float* Zall, const float* means,
                                                const float* cnrm, float* nc, float* ns) {
  int m = blockIdx.z;
  const float* x = (m < 2 ? content : style) + (size_t)(m & 1) * CN;
  float* outp = (m < 2 ? nc : ns) + (size_t)(m & 1) * CN;
  const float* Zm = Zall + (size_t)m*65536;
  const float* mean = means + m*C_;
  __shared__ float As[16][68], Bs[16][64];
  int t = threadIdx.x, tx = t & 15, ty = t >> 4;
  int n0 = blockIdx.x * 64, m0 = blockIdx.y * 64;
  float acc[4][4] = {};
  for (int k0 = 0; k0 < 256; k0 += 16) {
#pragma unroll
    for (int l = 0; l < 4; l++) {
      int e = t + l*256;
      { int kk = e & 15, mm = e >> 4; As[kk][mm] = Zm[(size_t)(m0+mm)*256 + k0+kk]; }
      { int nn = e & 63, kk = e >> 6;
        Bs[kk][nn] = x[(size_t)(k0+kk)*N_ + n0+nn] - mean[k0+kk]; }
    }
    __syncthreads();
#pragma unroll
    for (int kk = 0; kk < 16; kk++) {
      float4 b = *(const float4*)&Bs[kk][tx*4];
      fma16(acc, As[kk][ty*4+0], As[kk][ty*4+1], As[kk][ty*4+2], As[kk][ty*4+3], b);
    }
    __syncthreads();
  }
  float scale = 1.0f / sqrtf(cnrm[m]);
#pragma unroll
  for (int i = 0; i < 4; i++) {
    float4 o = make_float4(acc[i][0]*scale, acc[i][1]*scale, acc[i][2]*scale, acc[i][3]*scale);
    *(float4*)&outp[(size_t)(m0+ty*4+i)*N_ + n0 + tx*4] = o;
  }
}

// ---------------- per-pixel channel sum-of-squares of ns ----------------
__global__ __launch_bounds__(256) void k_ssq(const float* ns, float* ssq) {
  int b = blockIdx.y; int p = blockIdx.x * 256 + threadIdx.x;
  float acc = 0.f;
  for (int c = 0; c < C_; c++) { float v = ns[(size_t)b*CN + (size_t)c*N_ + p]; acc += v*v; }
  ssq[b*N_ + p] = acc;
}

// ---------------- patch reciprocal norms ----------------
__global__ __launch_bounds__(256) void k_rnorm(const float* ssq, float* rnorm) {
  int b = blockIdx.y; int s = blockIdx.x * 256 + threadIdx.x;
  int sy = s >> 6, sx = s & 63;
  float sum = 0.f;
#pragma unroll
  for (int ky = 0; ky < 3; ky++)
#pragma unroll
    for (int kx = 0; kx < 3; kx++)
      sum += ssq[b*N_ + refl(sy+ky-1)*64 + refl(sx+kx-1)];
  rnorm[b*N_ + s] = 1.f / (sqrtf(sum) + EPSF);
}

// ---------------- transpose + 3-way bf16 split for ONE batch: [c][v] -> [v][c] h/m/l ----------------
// z=0: nc_b -> ncT planes ; z=1: ns_b -> nsT planes. v = h+m+l to ~2^-27 rel.
__global__ __launch_bounds__(256) void k_split(const float* nc_b, const float* ns_b,
                                               unsigned short* ncTh, unsigned short* ncTm,
                                               unsigned short* ncTl,
                                               unsigned short* nsTh, unsigned short* nsTm,
                                               unsigned short* nsTl) {
  int w = blockIdx.z;
  const float* src = w ? ns_b : nc_b;
  unsigned short* dh = w ? nsTh : ncTh;
  unsigned short* dm = w ? nsTm : ncTm;
  unsigned short* dl = w ? nsTl : ncTl;
  int u0 = blockIdx.x * 32, c0 = blockIdx.y * 32;
  __shared__ float tile[32][33];
  int t = threadIdx.x;
#pragma unroll
  for (int l = 0; l < 4; l++) {
    int e = t + l*256; int cc = e >> 5, uu = e & 31;
    tile[cc][uu] = src[(size_t)(c0+cc)*N_ + u0+uu];
  }
  __syncthreads();
#pragma unroll
  for (int l = 0; l < 4; l++) {
    int e = t + l*256; int uu = e >> 5, cc = e & 31;
    float v = tile[cc][uu];
    unsigned short h = f2bf(v);
    float r1 = v - bf2f(h);
    unsigned short m = f2bf(r1);
    float r2 = r1 - bf2f(m);
    unsigned short lo = f2bf(r2);
    size_t o = (size_t)(u0+uu)*C_ + c0+cc;
    dh[o] = h; dm[o] = m; dl[o] = lo;
  }
}

// ---------------- Gram via 3-way-split bf16 MFMA (128x128 tile, 512 thr) + fused x-blur ----------------
// G = hh + hm + mh + hl + lh + mm  (6 x mfma_f32_16x16x32_bf16; dropped terms <= 2^-27 rel
// -> fp32-accurate scores, zero argmax-flip risk vs the np fp32 reference).
// Wave tiling: 8 waves, rows wv*32..+31 (wv=wave>>1), cols wu*64..+63 (wu=wave&1), 2x4 16x16 tiles.
// A-frag [m=lane&15][k=quad*8+j] (m120); B-frag symmetric; C/D col=lane&15,row=quad*4+reg (m89/m91).
// LDS stride 40 ushorts: 16B-aligned b128 frags, 2-way banks (free). Plain float4 staging
// (GLL needs unpadded rows; r10 note). acc = 32 VGPR, frags short-lived -> no VGPR cliff.
__global__ __launch_bounds__(512) void k_gram(const unsigned short* Ah_g, const unsigned short* Am_g,
                                              const unsigned short* Al_g,
                                              const unsigned short* Bh_g, const unsigned short* Bm_g,
                                              const unsigned short* Bl_g, float* Hx) {
  __shared__ unsigned short sm[6*128*LSTR];  // 61440 B; epilogue Gs[64][133] fp32 (34048 B) unioned
  const int P = 128*LSTR;
  int t = threadIdx.x;
  int v0 = blockIdx.y * 128, u0 = blockIdx.x * 128;
  int wave = t >> 6, lane = t & 63;
  int wv = wave >> 1, wu = wave & 1;
  int lx16 = lane & 15, quad = lane >> 4;
  int srow = t >> 2, sseg = (t & 3) * 8;     // 512 thr = 128 rows x 4 segs of 8 ushort (16 B)
  f32x4 acc[2][4];
#pragma unroll
  for (int i = 0; i < 2; i++)
#pragma unroll
    for (int j = 0; j < 4; j++) acc[i][j] = (f32x4){0.f, 0.f, 0.f, 0.f};

  for (int k0 = 0; k0 < 256; k0 += 32) {
    __syncthreads();
    {
      size_t goA = (size_t)(v0 + srow)*C_ + k0 + sseg;
      size_t goB = (size_t)(u0 + srow)*C_ + k0 + sseg;
      int lo_ = srow*LSTR + sseg;
      *(float4*)&sm[0*P + lo_] = *(const float4*)&Ah_g[goA];
      *(float4*)&sm[1*P + lo_] = *(const float4*)&Am_g[goA];
      *(float4*)&sm[2*P + lo_] = *(const float4*)&Al_g[goA];
      *(float4*)&sm[3*P + lo_] = *(const float4*)&Bh_g[goB];
      *(float4*)&sm[4*P + lo_] = *(const float4*)&Bm_g[goB];
      *(float4*)&sm[5*P + lo_] = *(const float4*)&Bl_g[goB];
    }
    __syncthreads();
#pragma unroll
    for (int mt = 0; mt < 2; mt++) {
      int arow = (wv*32 + mt*16 + lx16)*LSTR + quad*8;
      bf16x8 ah = *(const bf16x8*)&sm[0*P + arow];
      bf16x8 am = *(const bf16x8*)&sm[1*P + arow];
      bf16x8 al = *(const bf16x8*)&sm[2*P + arow];
#pragma unroll
      for (int nt = 0; nt < 4; nt++) {
        int brow = (wu*64 + nt*16 + lx16)*LSTR + quad*8;
        bf16x8 bh = *(const bf16x8*)&sm[3*P + brow];
        bf16x8 bm = *(const bf16x8*)&sm[4*P + brow];
        bf16x8 bl = *(const bf16x8*)&sm[5*P + brow];
        f32x4 a = acc[mt][nt];
        a = __builtin_amdgcn_mfma_f32_16x16x32_bf16(ah, bh, a, 0, 0, 0);
        a = __builtin_amdgcn_mfma_f32_16x16x32_bf16(ah, bm, a, 0, 0, 0);
        a = __builtin_amdgcn_mfma_f32_16x16x32_bf16(am, bh, a, 0, 0, 0);
        a = __builtin_amdgcn_mfma_f32_16x16x32_bf16(ah, bl, a, 0, 0, 0);
        a = __builtin_amdgcn_mfma_f32_16x16x32_bf16(al, bh, a, 0, 0, 0);
        a = __builtin_amdgcn_mfma_f32_16x16x32_bf16(am, bm, a, 0, 0, 0);
        acc[mt][nt] = a;
      }
    }
  }
  // epilogue: per 64-row half h, x-diagonal blur. Gs stride 133 fp32.
  float* Gs = (float*)sm;
  int btx = t & 15, bty = t >> 4;            // bty 0..31
#pragma unroll
  for (int h = 0; h < 2; h++) {
    __syncthreads();
    if ((wv >> 1) == h) {                    // waves with wv in {2h,2h+1} own rows h*64..+63
      int rbase = (wv & 1) * 32;
#pragma unroll
      for (int mt = 0; mt < 2; mt++)
#pragma unroll
        for (int nt = 0; nt < 4; nt++)
#pragma unroll
          for (int i = 0; i < 4; i++)
            Gs[(rbase + mt*16 + quad*4 + i)*133 + wu*64 + nt*16 + lx16] = acc[mt][nt][i];
    }
    __syncthreads();
#pragma unroll
    for (int i = 0; i < 2; i++) {
      int px = bty*2 + i;
      int xm = refl(px-1), xp = refl(px+1);
#pragma unroll
      for (int jh = 0; jh < 2; jh++) {
        int ub = jh*64;
        float tmp[4];
#pragma unroll
        for (int j = 0; j < 4; j++) {
          int sx = btx*4 + j;
          int smm = refl(sx-1), sp = refl(sx+1);
          tmp[j] = Gs[xm*133 + ub + smm] + Gs[px*133 + ub + sx] + Gs[xp*133 + ub + sp];
        }
        *(float4*)&Hx[(size_t)(v0 + h*64 + px)*N_ + u0 + ub + btx*4] =
            make_float4(tmp[0], tmp[1], tmp[2], tmp[3]);
      }
    }
  }
}

// ---------------- y-diagonal blur of Hx + argmax ----------------
__global__ __launch_bounds__(256) void k_argmax(const float* Hx, const float* rnorm,
                                                int* idx, int b) {
  int p = blockIdx.x, t = threadIdx.x;
  int py = p >> 6, px = p & 63;
  size_t r0 = (size_t)(refl(py-1)*64 + px) * N_;
  size_t r1 = (size_t)p * N_;
  size_t r2 = (size_t)(refl(py+1)*64 + px) * N_;
  float bv = -1e30f; int bs = 0;
  for (int s = t; s < N_; s += 256) {
    int sy = s >> 6, sx = s & 63;
    int u0 = refl(sy-1)*64 + sx, u2 = refl(sy+1)*64 + sx;
    float acc = Hx[r0 + u0] + Hx[r1 + s] + Hx[r2 + u2];
    float sc = acc * rnorm[b*N_ + s];
    if (sc > bv) { bv = sc; bs = s; }
  }
  __shared__ float sv[256]; __shared__ int si[256];
  sv[t] = bv; si[t] = bs; __syncthreads();
  for (int off = 128; off > 0; off >>= 1) {
    if (t < off) {
      if (sv[t+off] > sv[t] || (sv[t+off] == sv[t] && si[t+off] < si[t])) {
        sv[t] = sv[t+off]; si[t] = si[t+off];
      }
    }
    __syncthreads();
  }
  if (!t) idx[b*N_ + p] = si[0];
}

// ---------------- deconv gather for batch b: recont_b[p][c] from bf16 triple ----------------
__global__ __launch_bounds__(256) void k_recon(const unsigned short* nsTh,
                                               const unsigned short* nsTm,
                                               const unsigned short* nsTl,
                                               const int* idx_b, float* recont_b) {
  int p = blockIdx.x, c = threadIdx.x;
  int py = p >> 6, px = p & 63;
  float acc = 0.f;
#pragma unroll
  for (int dy = 0; dy < 3; dy++)
#pragma unroll
    for (int dx = 0; dx < 3; dx++) {
      int q = refl(py+dy-1)*64 + refl(px+dx-1);
      int s = idx_b[q];
      int sy = s >> 6, sx = s & 63;
      size_t o = (size_t)(refl(sy+1-dy)*64 + refl(sx+1-dx))*C_ + c;
      acc += bf2f(nsTh[o]) + bf2f(nsTm[o]) + bf2f(nsTl[o]);
    }
  float dc = ((py==0||py==63)?2.f:3.f) * ((px==0||px==63)?2.f:3.f);
  recont_b[(size_t)p*C_ + c] = acc / dc;
}

// ---------------- coloring (both batches via grid.z) ----------------
__global__ __launch_bounds__(256) void k_color(const float* Yall, const float* recont_all,
                                               const float* cnrm, const float* means,
                                               float* out_all) {
  int b = blockIdx.z;
  const float* Ym = Yall + (size_t)(2+b)*65536;
  const float* recont = recont_all + (size_t)b*CN;
  const float* smean = means + (2+b)*C_;
  float* out = out_all + (size_t)b*CN;
  __shared__ float As[16][68], Bs[16][68];
  int t = threadIdx.x, tx = t & 15, ty = t >> 4;
  int n0 = blockIdx.x * 64, m0 = blockIdx.y * 64;
  float acc[4][4] = {};
  for (int k0 = 0; k0 < 256; k0 += 16) {
#pragma unroll
    for (int l = 0; l < 4; l++) {
      int e = t + l*256;
      int kk = e & 15, q = e >> 4;
      As[kk][q] = Ym[(size_t)(m0+q)*256 + k0+kk];
      Bs[kk][q] = recont[(size_t)(n0+q)*256 + k0+kk];
    }
    __syncthreads();
#pragma unroll
    for (int kk = 0; kk < 16; kk++) {
      float4 b4 = make_float4(Bs[kk][tx*4+0], Bs[kk][tx*4+1], Bs[kk][tx*4+2], Bs[kk][tx*4+3]);
      fma16(acc, As[kk][ty*4+0], As[kk][ty*4+1], As[kk][ty*4+2], As[kk][ty*4+3], b4);
    }
    __syncthreads();
  }
  float scale = sqrtf(cnrm[2+b]);
#pragma unroll
  for (int i = 0; i < 4; i++) {
    int r = m0 + ty*4 + i;
    float sm = smean[r];
    float4 o = make_float4(acc[i][0]*scale + sm, acc[i][1]*scale + sm,
                           acc[i][2]*scale + sm, acc[i][3]*scale + sm);
    *(float4*)&out[(size_t)r*N_ + n0 + tx*4] = o;
  }
}

extern "C" void kernel_launch(void* const* d_in, const int* in_sizes, int n_in,
                              void* d_out, int out_size, void* d_ws, size_t ws_size,
                              hipStream_t stream) {
  const float* content = (const float*)d_in[0];
  const float* style   = (const float*)d_in[1];
  float* out = (float*)d_out;

  // workspace layout (floats); total ~102 MiB (verified budget — r13's overflow fixed)
  float* F = (float*)d_ws;
  float* means  = F + 0;         // 4*256
  float* cnrm   = F + 1024;      // 4
  float* Y      = F + 264192;    // NS buffers, 256KB each region of 4 matrices
  float* Z      = F + 526336;
  float* Y2     = F + 788480;    // free after NS (NS_ITERS=6 even -> results in Y,Z)
  float* Z2     = F + 1050624;
  float* T      = F + 1312768;
  float* nc     = F + 1574912;   // 2*CN fp32 (dead after split(1))
  float* ns     = F + 3672064;   // 2*CN fp32 (dead after split(1))
  float* nstslot= F + 5769216;   // old ns_t slot: 2*CN floats = 4 bf16 planes
  float* recont = F + 7866368;   // 2*CN fp32, written per batch at recon(b)
  float* ssq    = F + 9963520;   // 2*4096
  float* rnorm  = F + 9971712;   // 2*4096
  int*   idx    = (int*)(F + 9979904); // 2*4096
  float* Hx     = F + 9988096;   // 4096*4096 (16.7M floats)

  // cov-phase aliases inside Hx (dead until k_gram at step 8):
  //  - covsp: 4 m x 3 planes x CN ushorts = 12.58M ushorts = 6.29M floats (25.2 MB)
  //  - covp : KSPLIT(16) x 4 x 65536 = 4.19M floats; both consumed by covred before NS.
  unsigned short* covsp = (unsigned short*)Hx;
  float* covp = Hx + 3*(size_t)CN*2;   // = Hx + 6291456 floats

  // per-batch bf16 planes (each CN ushorts = 2 MB), race-checked vs launch order:
  //  - nsT h/m/l + ncT h: the 4 slots of the old ns_t region (recon reads nsT* only)
  //  - ncT m: Y2+Z2 (free post-NS)
  //  - ncT l: recont[1] head — written at split(b), dead after gram(b); recon(1)
  //    overwrites it only AFTER gram(1). recon(0) writes recont[0] (disjoint).
  unsigned short* nsTh = (unsigned short*)nstslot;
  unsigned short* nsTm = (unsigned short*)nstslot + (size_t)CN;
  unsigned short* nsTl = (unsigned short*)nstslot + 2*(size_t)CN;
  unsigned short* ncTh = (unsigned short*)nstslot + 3*(size_t)CN;
  unsigned short* ncTm = (unsigned short*)Y2;
  unsigned short* ncTl = (unsigned short*)(recont + CN);

  // 1-4. means, bf16-split, MFMA cov partials, trace, covred+nsinit
  k_mean<<<dim3(256,4), 256, 0, stream>>>(content, style, means);
  k_splitcov<<<dim3(1024,4), 256, 0, stream>>>(content, style, covsp);
  k_covmm<<<dim3(KSPLIT,4,4), 512, 0, stream>>>(covsp, covp);
  k_trace2<<<4, 256, 0, stream>>>(covp, means, cnrm);
  k_covred_init<<<dim3(256,4), 256, 0, stream>>>(covp, means, cnrm, Y, Z);
  // 5. NS iterations (6, even -> results land back in Y,Z; Y2/Z2/T free afterwards)
  float *Ya = Y, *Za = Z, *Yb = Y2, *Zb = Z2;
  for (int it = 0; it < NS_ITERS; it++) {
    k_nsA<<<dim3(64,4), 256, 0, stream>>>(Za, Ya, T);
    k_nsB<<<dim3(64,4,2), 256, 0, stream>>>(Ya, Za, T, Yb, Zb);
    float* tmp;
    tmp = Ya; Ya = Yb; Yb = tmp;
    tmp = Za; Za = Zb; Zb = tmp;
  }
  // 6. whitening
  k_whiten<<<dim3(64,4,4), 256, 0, stream>>>(content, style, Za, means, cnrm, nc, ns);
  // 7. patch norms
  k_ssq<<<dim3(16,2), 256, 0, stream>>>(ns, ssq);
  k_rnorm<<<dim3(16,2), 256, 0, stream>>>(ssq, rnorm);
  // 8. per batch: split -> MFMA gram + x-blur -> y-blur+argmax -> recon
  for (int b = 0; b < 2; b++) {
    k_split<<<dim3(128,8,2), 256, 0, stream>>>(nc + (size_t)b*CN, ns + (size_t)b*CN,
                                               ncTh, ncTm, ncTl, nsTh, nsTm, nsTl);
    k_gram<<<dim3(32,32), 512, 0, stream>>>(ncTh, ncTm, ncTl, nsTh, nsTm, nsTl, Hx);
    k_argmax<<<4096, 256, 0, stream>>>(Hx, rnorm, idx, b);
    k_recon<<<4096, 256, 0, stream>>>(nsTh, nsTm, nsTl, idx + (size_t)b*N_,
                                      recont + (size_t)b*CN);
  }
  // 9. coloring
  k_color<<<dim3(64,4,2), 256, 0, stream>>>(Ya, recont, cnrm, means, out);
}

// Round 2
// 445.199 us; speedup vs baseline: 1.1845x; 1.1136x over previous
//
#include <hip/hip_runtime.h>
#include <hip/hip_bf16.h>

#define C_ 256
#define N_ 4096
#define CN (C_*N_)
#define EPSF 1e-5f
#define NS_ITERS 6
#define KSPLIT 16  // split-K for MFMA cov partials
#define LSTR 40   // LDS row stride in ushort: 80 B, 16B-aligned, 2-way banks (free)

typedef _Float16 f16x8 __attribute__((ext_vector_type(8)));
typedef float f32x4 __attribute__((ext_vector_type(4)));

__device__ __forceinline__ int refl(int t) {
  return t < 0 ? -t : (t > 63 ? 126 - t : t);
}

// fp16 2-way split: v = h + l exact to ~2^-22 rel (Sterbenz: v-(float)h exact in fp32,
// then one RNE to fp16). Products hh+hl+lh drop only ll ~ 2^-22 rel — below the fp32
// reference's own accumulation noise (sqrt(2304)*2^-24 ~ 3e-6).
__device__ __forceinline__ unsigned short f2h(float x) {
  _Float16 h = (_Float16)x;
  return __builtin_bit_cast(unsigned short, h);
}
__device__ __forceinline__ float h2f(unsigned short u) {
  return (float)__builtin_bit_cast(_Float16, u);
}

__device__ __forceinline__ void fma16(float acc[4][4], float a0, float a1, float a2, float a3, float4 b) {
  acc[0][0] += a0*b.x; acc[0][1] += a0*b.y; acc[0][2] += a0*b.z; acc[0][3] += a0*b.w;
  acc[1][0] += a1*b.x; acc[1][1] += a1*b.y; acc[1][2] += a1*b.z; acc[1][3] += a1*b.w;
  acc[2][0] += a2*b.x; acc[2][1] += a2*b.y; acc[2][2] += a2*b.z; acc[2][3] += a2*b.w;
  acc[3][0] += a3*b.x; acc[3][1] += a3*b.y; acc[3][2] += a3*b.z; acc[3][3] += a3*b.w;
}

// ---------------- means ----------------
__global__ __launch_bounds__(256) void k_mean(const float* content, const float* style,
                                              float* means) {
  int c = blockIdx.x, m = blockIdx.y, t = threadIdx.x;
  const float* x = (m < 2 ? content : style) + (size_t)(m & 1) * CN + (size_t)c * N_;
  float s = 0.f;
  for (int i = t; i < N_; i += 256) s += x[i];
  __shared__ float red[256];
  red[t] = s; __syncthreads();
  for (int off = 128; off > 0; off >>= 1) { if (t < off) red[t] += red[t + off]; __syncthreads(); }
  if (t == 0) means[m * C_ + c] = red[0] * (1.f / N_);
}

// ---------------- 2-way fp16 split of raw content/style for MFMA cov ----------------
// [m][plane][c][n], n contiguous (no transpose needed; cov = X·X^T reads rows for both).
__global__ __launch_bounds__(256) void k_splitcov(const float* content, const float* style,
                                                  unsigned short* sp) {
  int m = blockIdx.y;
  const float* x = (m < 2 ? content : style) + (size_t)(m & 1) * CN;
  size_t base = (size_t)m * 2 * (size_t)CN;
  size_t i = ((size_t)blockIdx.x * 256 + threadIdx.x) * 4;
  float4 v = *(const float4*)&x[i];
  float vv[4] = {v.x, v.y, v.z, v.w};
  unsigned short h[4], lo[4];
#pragma unroll
  for (int j = 0; j < 4; j++) {
    unsigned short hh = f2h(vv[j]);
    float r1 = vv[j] - h2f(hh);
    h[j] = hh; lo[j] = f2h(r1);
  }
  *(ushort4*)&sp[base + i]      = make_ushort4(h[0], h[1], h[2], h[3]);
  *(ushort4*)&sp[base + CN + i] = make_ushort4(lo[0], lo[1], lo[2], lo[3]);
}

// ---------------- covariance raw sums via 3-term fp16 MFMA, split-K ----------------
// 128x128 tile, 8 waves (wv rows of 32, wu cols of 64), 3 x mfma_f32_16x16x32_f16
// per fragment (hh+hl+lh). Grid: (KSPLIT, 4 tiles, 4 m) = 256 blocks.
__global__ __launch_bounds__(512) void k_covmm(const unsigned short* sp, float* covp) {
  __shared__ unsigned short sm[4*128*LSTR];   // 40960 B
  const int P = 128*LSTR;
  int t = threadIdx.x;
  int kc = blockIdx.x, m = blockIdx.z;
  int ti = blockIdx.y >> 1, tj = blockIdx.y & 1;
  const unsigned short* Xh = sp + (size_t)m * 2 * (size_t)CN;
  const unsigned short* Xl = Xh + CN;
  int v0 = ti * 128, u0 = tj * 128;
  int wave = t >> 6, lane = t & 63;
  int wv = wave >> 1, wu = wave & 1;
  int lx16 = lane & 15, quad = lane >> 4;
  int srow = t >> 2, sseg = (t & 3) * 8;   // 512 thr = 128 rows x 4 segs of 8 ushort
  f32x4 acc[2][4];
#pragma unroll
  for (int i = 0; i < 2; i++)
#pragma unroll
    for (int j = 0; j < 4; j++) acc[i][j] = (f32x4){0.f, 0.f, 0.f, 0.f};

  int kbeg = kc * (N_ / KSPLIT), kend = kbeg + (N_ / KSPLIT);
  for (int k0 = kbeg; k0 < kend; k0 += 32) {
    __syncthreads();
    {
      size_t goA = (size_t)(v0 + srow) * N_ + k0 + sseg;
      size_t goB = (size_t)(u0 + srow) * N_ + k0 + sseg;
      int lo_ = srow * LSTR + sseg;
      *(float4*)&sm[0*P + lo_] = *(const float4*)&Xh[goA];
      *(float4*)&sm[1*P + lo_] = *(const float4*)&Xl[goA];
      *(float4*)&sm[2*P + lo_] = *(const float4*)&Xh[goB];
      *(float4*)&sm[3*P + lo_] = *(const float4*)&Xl[goB];
    }
    __syncthreads();
#pragma unroll
    for (int mt = 0; mt < 2; mt++) {
      int arow = (wv*32 + mt*16 + lx16)*LSTR + quad*8;
      f16x8 ah = *(const f16x8*)&sm[0*P + arow];
      f16x8 al = *(const f16x8*)&sm[1*P + arow];
#pragma unroll
      for (int nt = 0; nt < 4; nt++) {
        int brow = (wu*64 + nt*16 + lx16)*LSTR + quad*8;
        f16x8 bh = *(const f16x8*)&sm[2*P + brow];
        f16x8 bl = *(const f16x8*)&sm[3*P + brow];
        f32x4 a = acc[mt][nt];
        a = __builtin_amdgcn_mfma_f32_16x16x32_f16(ah, bh, a, 0, 0, 0);
        a = __builtin_amdgcn_mfma_f32_16x16x32_f16(ah, bl, a, 0, 0, 0);
        a = __builtin_amdgcn_mfma_f32_16x16x32_f16(al, bh, a, 0, 0, 0);
        acc[mt][nt] = a;
      }
    }
  }
  // C/D: col=lane&15, row=quad*4+i (m89/m91)
  float* O = covp + ((size_t)kc*4 + m) * 65536;
#pragma unroll
  for (int mt = 0; mt < 2; mt++)
#pragma unroll
    for (int nt = 0; nt < 4; nt++)
#pragma unroll
      for (int i = 0; i < 4; i++)
        O[(size_t)(v0 + wv*32 + mt*16 + quad*4 + i)*C_ + (u0 + wu*64 + nt*16 + lx16)] =
            acc[mt][nt][i];
}

// ---------------- trace from partials -> cnrm = (tr/256)*1.3 ----------------
__global__ __launch_bounds__(256) void k_trace2(const float* covp, const float* means,
                                                float* cnrm) {
  int m = blockIdx.x, t = threadIdx.x;
  float s = 0.f;
#pragma unroll
  for (int kc = 0; kc < KSPLIT; kc++)
    s += covp[((size_t)kc*4 + m)*65536 + (size_t)t*257];
  float mi = means[m*C_ + t];
  float d = (s - (float)N_*mi*mi) * (1.f/(float)(N_-1));
  __shared__ float red[256];
  red[t] = d; __syncthreads();
  for (int off = 128; off > 0; off >>= 1) { if (t < off) red[t] += red[t + off]; __syncthreads(); }
  if (!t) cnrm[m] = red[0] * (1.3f/256.f);
}

// ---------------- merged covred + nsinit ----------------
__global__ __launch_bounds__(256) void k_covred_init(const float* covp, const float* means,
                                                     const float* cnrm, float* Y, float* Z) {
  int i = blockIdx.x, m = blockIdx.y, j = threadIdx.x;
  float s = 0.f;
#pragma unroll
  for (int kc = 0; kc < KSPLIT; kc++)
    s += covp[((size_t)kc*4 + m)*65536 + (size_t)i*C_ + j];
  float mi = means[m*C_ + i], mj = means[m*C_ + j];
  float cv = (s - (float)N_*mi*mj) * (1.f/(float)(N_-1));
  size_t o = (size_t)m*65536 + (size_t)i*C_ + j;
  Y[o] = cv / cnrm[m];
  Z[o] = (i == j) ? 1.f : 0.f;
}

// ---------------- NS phase A: T = 3I - Z*Y ----------------
__global__ __launch_bounds__(256) void k_nsA(const float* Zin, const float* Yin, float* T) {
  int m = blockIdx.y;
  const float* A = Zin + (size_t)m*65536;
  const float* B = Yin + (size_t)m*65536;
  float* O = T + (size_t)m*65536;
  __shared__ float As[32][33], Bs[32][33];
  int t = threadIdx.x, tx = t & 15, ty = t >> 4;
  int m0 = (blockIdx.x >> 3) * 32, n0 = (blockIdx.x & 7) * 32;
  float acc[2][2] = {};
  for (int k0 = 0; k0 < 256; k0 += 32) {
#pragma unroll
    for (int l = 0; l < 4; l++) {
      int e = t + l * 256;
      int rr = e >> 5, cc = e & 31;
      As[rr][cc] = A[(size_t)(m0+rr)*256 + k0+cc];
      Bs[rr][cc] = B[(size_t)(k0+rr)*256 + n0+cc];
    }
    __syncthreads();
#pragma unroll
    for (int kk = 0; kk < 32; kk++) {
      float a0 = As[ty*2][kk], a1 = As[ty*2+1][kk];
      float b0 = Bs[kk][tx*2], b1 = Bs[kk][tx*2+1];
      acc[0][0] += a0*b0; acc[0][1] += a0*b1; acc[1][0] += a1*b0; acc[1][1] += a1*b1;
    }
    __syncthreads();
  }
#pragma unroll
  for (int a = 0; a < 2; a++)
#pragma unroll
    for (int b = 0; b < 2; b++) {
      int r = m0 + ty*2 + a, c = n0 + tx*2 + b;
      O[(size_t)r*256 + c] = (r == c) ? 3.f - acc[a][b] : -acc[a][b];
    }
}

// ---------------- NS phase B ----------------
__global__ __launch_bounds__(256) void k_nsB(const float* Yin, const float* Zin, const float* T,
                                             float* Yout, float* Zout) {
  int m = blockIdx.y, z = blockIdx.z;
  const float* A = (z == 0 ? Yin : T) + (size_t)m*65536;
  const float* B = (z == 0 ? T : Zin) + (size_t)m*65536;
  float* O = (z == 0 ? Yout : Zout) + (size_t)m*65536;
  __shared__ float As[32][33], Bs[32][33];
  int t = threadIdx.x, tx = t & 15, ty = t >> 4;
  int m0 = (blockIdx.x >> 3) * 32, n0 = (blockIdx.x & 7) * 32;
  float acc[2][2] = {};
  for (int k0 = 0; k0 < 256; k0 += 32) {
#pragma unroll
    for (int l = 0; l < 4; l++) {
      int e = t + l * 256;
      int rr = e >> 5, cc = e & 31;
      As[rr][cc] = A[(size_t)(m0+rr)*256 + k0+cc];
      Bs[rr][cc] = B[(size_t)(k0+rr)*256 + n0+cc];
    }
    __syncthreads();
#pragma unroll
    for (int kk = 0; kk < 32; kk++) {
      float a0 = As[ty*2][kk], a1 = As[ty*2+1][kk];
      float b0 = Bs[kk][tx*2], b1 = Bs[kk][tx*2+1];
      acc[0][0] += a0*b0; acc[0][1] += a0*b1; acc[1][0] += a1*b0; acc[1][1] += a1*b1;
    }
    __syncthreads();
  }
#pragma unroll
  for (int a = 0; a < 2; a++)
#pragma unroll
    for (int b = 0; b < 2; b++)
      O[(size_t)(m0+ty*2+a)*256 + n0+tx*2+b] = 0.5f * acc[a][b];
}

// ---------------- whiten ----------------
__global__ __launch_bounds__(256) void k_whiten(const float* content, const float* style,
                                                const float* Zall, const float* means,
                                                const float* cnrm, float* nc, float* ns) {
  int m = blockIdx.z;
  const float* x = (m < 2 ? content : style) + (size_t)(m & 1) * CN;
  float* outp = (m < 2 ? nc : ns) + (size_t)(m & 1) * CN;
  const float* Zm = Zall + (size_t)m*65536;
  const float* mean = means + m*C_;
  __shared__ float As[16][68], Bs[16][64];
  int t = threadIdx.x, tx = t & 15, ty = t >> 4;
  int n0 = blockIdx.x * 64, m0 = blockIdx.y * 64;
  float acc[4][4] = {};
  for (int k0 = 0; k0 < 256; k0 += 16) {
#pragma unroll
    for (int l = 0; l < 4; l++) {
      int e = t + l*256;
      { int kk = e & 15, mm = e >> 4; As[kk][mm] = Zm[(size_t)(m0+mm)*256 + k0+kk]; }
      { int nn = e & 63, kk = e >> 6;
        Bs[kk][nn] = x[(size_t)(k0+kk)*N_ + n0+nn] - mean[k0+kk]; }
    }
    __syncthreads();
#pragma unroll
    for (int kk = 0; kk < 16; kk++) {
      float4 b = *(const float4*)&Bs[kk][tx*4];
      fma16(acc, As[kk][ty*4+0], As[kk][ty*4+1], As[kk][ty*4+2], As[kk][ty*4+3], b);
    }
    __syncthreads();
  }
  float scale = 1.0f / sqrtf(cnrm[m]);
#pragma unroll
  for (int i = 0; i < 4; i++) {
    float4 o = make_float4(acc[i][0]*scale, acc[i][1]*scale, acc[i][2]*scale, acc[i][3]*scale);
    *(float4*)&outp[(size_t)(m0+ty*4+i)*N_ + n0 + tx*4] = o;
  }
}

// ---------------- per-pixel channel sum-of-squares of ns ----------------
__global__ __launch_bounds__(256) void k_ssq(const float* ns, float* ssq) {
  int b = blockIdx.y; int p = blockIdx.x * 256 + threadIdx.x;
  float acc = 0.f;
  for (int c = 0; c < C_; c++) { float v = ns[(size_t)b*CN + (size_t)c*N_ + p]; acc += v*v; }
  ssq[b*N_ + p] = acc;
}

// ---------------- patch reciprocal norms ----------------
__global__ __launch_bounds__(256) void k_rnorm(const float* ssq, float* rnorm) {
  int b = blockIdx.y; int s = blockIdx.x * 256 + threadIdx.x;
  int sy = s >> 6, sx = s & 63;
  float sum = 0.f;
#pragma unroll
  for (int ky = 0; ky < 3; ky++)
#pragma unroll
    for (int kx = 0; kx < 3; kx++)
      sum += ssq[b*N_ + refl(sy+ky-1)*64 + refl(sx+kx-1)];
  rnorm[b*N_ + s] = 1.f / (sqrtf(sum) + EPSF);
}

// ---------------- transpose + 2-way fp16 split for ONE batch: [c][v] -> [v][c] h/l ----------------
// z=0: nc_b -> ncT planes ; z=1: ns_b -> nsT planes. v = h+l to ~2^-22 rel.
__global__ __launch_bounds__(256) void k_split(const float* nc_b, const float* ns_b,
                                               unsigned short* ncTh, unsigned short* ncTl,
                                               unsigned short* nsTh, unsigned short* nsTl) {
  int w = blockIdx.z;
  const float* src = w ? ns_b : nc_b;
  unsigned short* dh = w ? nsTh : ncTh;
  unsigned short* dl = w ? nsTl : ncTl;
  int u0 = blockIdx.x * 32, c0 = blockIdx.y * 32;
  __shared__ float tile[32][33];
  int t = threadIdx.x;
#pragma unroll
  for (int l = 0; l < 4; l++) {
    int e = t + l*256; int cc = e >> 5, uu = e & 31;
    tile[cc][uu] = src[(size_t)(c0+cc)*N_ + u0+uu];
  }
  __syncthreads();
#pragma unroll
  for (int l = 0; l < 4; l++) {
    int e = t + l*256; int uu = e >> 5, cc = e & 31;
    float v = tile[cc][uu];
    unsigned short h = f2h(v);
    float r1 = v - h2f(h);
    unsigned short lo = f2h(r1);
    size_t o = (size_t)(u0+uu)*C_ + c0+cc;
    dh[o] = h; dl[o] = lo;
  }
}

// ---------------- Gram via 2-way-split fp16 MFMA (128x128 tile, 512 thr) + fused x-blur ----------------
// G = hh + hl + lh  (3 x mfma_f32_16x16x32_f16; dropped ll <= 2^-22 rel -> fp32-accurate
// scores, no argmax-flip risk vs the np fp32 reference).
// Wave tiling: 8 waves, rows wv*32..+31 (wv=wave>>1), cols wu*64..+63 (wu=wave&1), 2x4 16x16 tiles.
// A-frag [m=lane&15][k=quad*8+j] (m120); B-frag symmetric; C/D col=lane&15,row=quad*4+reg (m89/m91).
// LDS stride 40 ushorts: 16B-aligned b128 frags, 2-way banks (free). Plain float4 staging
// (GLL needs unpadded rows; r10 note). LDS 40960 B -> 3 blocks/CU (was 2 with 6 planes).
__global__ __launch_bounds__(512) void k_gram(const unsigned short* Ah_g, const unsigned short* Al_g,
                                              const unsigned short* Bh_g, const unsigned short* Bl_g,
                                              float* Hx) {
  __shared__ unsigned short sm[4*128*LSTR];  // 40960 B; epilogue Gs[64][133] fp32 (34048 B) unioned
  const int P = 128*LSTR;
  int t = threadIdx.x;
  int v0 = blockIdx.y * 128, u0 = blockIdx.x * 128;
  int wave = t >> 6, lane = t & 63;
  int wv = wave >> 1, wu = wave & 1;
  int lx16 = lane & 15, quad = lane >> 4;
  int srow = t >> 2, sseg = (t & 3) * 8;     // 512 thr = 128 rows x 4 segs of 8 ushort (16 B)
  f32x4 acc[2][4];
#pragma unroll
  for (int i = 0; i < 2; i++)
#pragma unroll
    for (int j = 0; j < 4; j++) acc[i][j] = (f32x4){0.f, 0.f, 0.f, 0.f};

  for (int k0 = 0; k0 < 256; k0 += 32) {
    __syncthreads();
    {
      size_t goA = (size_t)(v0 + srow)*C_ + k0 + sseg;
      size_t goB = (size_t)(u0 + srow)*C_ + k0 + sseg;
      int lo_ = srow*LSTR + sseg;
      *(float4*)&sm[0*P + lo_] = *(const float4*)&Ah_g[goA];
      *(float4*)&sm[1*P + lo_] = *(const float4*)&Al_g[goA];
      *(float4*)&sm[2*P + lo_] = *(const float4*)&Bh_g[goB];
      *(float4*)&sm[3*P + lo_] = *(const float4*)&Bl_g[goB];
    }
    __syncthreads();
#pragma unroll
    for (int mt = 0; mt < 2; mt++) {
      int arow = (wv*32 + mt*16 + lx16)*LSTR + quad*8;
      f16x8 ah = *(const f16x8*)&sm[0*P + arow];
      f16x8 al = *(const f16x8*)&sm[1*P + arow];
#pragma unroll
      for (int nt = 0; nt < 4; nt++) {
        int brow = (wu*64 + nt*16 + lx16)*LSTR + quad*8;
        f16x8 bh = *(const f16x8*)&sm[2*P + brow];
        f16x8 bl = *(const f16x8*)&sm[3*P + brow];
        f32x4 a = acc[mt][nt];
        a = __builtin_amdgcn_mfma_f32_16x16x32_f16(ah, bh, a, 0, 0, 0);
        a = __builtin_amdgcn_mfma_f32_16x16x32_f16(ah, bl, a, 0, 0, 0);
        a = __builtin_amdgcn_mfma_f32_16x16x32_f16(al, bh, a, 0, 0, 0);
        acc[mt][nt] = a;
      }
    }
  }
  // epilogue: per 64-row half h, x-diagonal blur. Gs stride 133 fp32.
  float* Gs = (float*)sm;
  int btx = t & 15, bty = t >> 4;            // bty 0..31
#pragma unroll
  for (int h = 0; h < 2; h++) {
    __syncthreads();
    if ((wv >> 1) == h) {                    // waves with wv in {2h,2h+1} own rows h*64..+63
      int rbase = (wv & 1) * 32;
#pragma unroll
      for (int mt = 0; mt < 2; mt++)
#pragma unroll
        for (int nt = 0; nt < 4; nt++)
#pragma unroll
          for (int i = 0; i < 4; i++)
            Gs[(rbase + mt*16 + quad*4 + i)*133 + wu*64 + nt*16 + lx16] = acc[mt][nt][i];
    }
    __syncthreads();
#pragma unroll
    for (int i = 0; i < 2; i++) {
      int px = bty*2 + i;
      int xm = refl(px-1), xp = refl(px+1);
#pragma unroll
      for (int jh = 0; jh < 2; jh++) {
        int ub = jh*64;
        float tmp[4];
#pragma unroll
        for (int j = 0; j < 4; j++) {
          int sx = btx*4 + j;
          int smm = refl(sx-1), sp = refl(sx+1);
          tmp[j] = Gs[xm*133 + ub + smm] + Gs[px*133 + ub + sx] + Gs[xp*133 + ub + sp];
        }
        *(float4*)&Hx[(size_t)(v0 + h*64 + px)*N_ + u0 + ub + btx*4] =
            make_float4(tmp[0], tmp[1], tmp[2], tmp[3]);
      }
    }
  }
}

// ---------------- y-diagonal blur of Hx + argmax ----------------
__global__ __launch_bounds__(256) void k_argmax(const float* Hx, const float* rnorm,
                                                int* idx, int b) {
  int p = blockIdx.x, t = threadIdx.x;
  int py = p >> 6, px = p & 63;
  size_t r0 = (size_t)(refl(py-1)*64 + px) * N_;
  size_t r1 = (size_t)p * N_;
  size_t r2 = (size_t)(refl(py+1)*64 + px) * N_;
  float bv = -1e30f; int bs = 0;
  for (int s = t; s < N_; s += 256) {
    int sy = s >> 6, sx = s & 63;
    int u0 = refl(sy-1)*64 + sx, u2 = refl(sy+1)*64 + sx;
    float acc = Hx[r0 + u0] + Hx[r1 + s] + Hx[r2 + u2];
    float sc = acc * rnorm[b*N_ + s];
    if (sc > bv) { bv = sc; bs = s; }
  }
  __shared__ float sv[256]; __shared__ int si[256];
  sv[t] = bv; si[t] = bs; __syncthreads();
  for (int off = 128; off > 0; off >>= 1) {
    if (t < off) {
      if (sv[t+off] > sv[t] || (sv[t+off] == sv[t] && si[t+off] < si[t])) {
        sv[t] = sv[t+off]; si[t] = si[t+off];
      }
    }
    __syncthreads();
  }
  if (!t) idx[b*N_ + p] = si[0];
}

// ---------------- deconv gather for batch b: recont_b[p][c] from fp16 pair ----------------
__global__ __launch_bounds__(256) void k_recon(const unsigned short* nsTh,
                                               const unsigned short* nsTl,
                                               const int* idx_b, float* recont_b) {
  int p = blockIdx.x, c = threadIdx.x;
  int py = p >> 6, px = p & 63;
  float acc = 0.f;
#pragma unroll
  for (int dy = 0; dy < 3; dy++)
#pragma unroll
    for (int dx = 0; dx < 3; dx++) {
      int q = refl(py+dy-1)*64 + refl(px+dx-1);
      int s = idx_b[q];
      int sy = s >> 6, sx = s & 63;
      size_t o = (size_t)(refl(sy+1-dy)*64 + refl(sx+1-dx))*C_ + c;
      acc += h2f(nsTh[o]) + h2f(nsTl[o]);
    }
  float dc = ((py==0||py==63)?2.f:3.f) * ((px==0||px==63)?2.f:3.f);
  recont_b[(size_t)p*C_ + c] = acc / dc;
}

// ---------------- coloring (both batches via grid.z) ----------------
__global__ __launch_bounds__(256) void k_color(const float* Yall, const float* recont_all,
                                               const float* cnrm, const float* means,
                                               float* out_all) {
  int b = blockIdx.z;
  const float* Ym = Yall + (size_t)(2+b)*65536;
  const float* recont = recont_all + (size_t)b*CN;
  const float* smean = means + (2+b)*C_;
  float* out = out_all + (size_t)b*CN;
  __shared__ float As[16][68], Bs[16][68];
  int t = threadIdx.x, tx = t & 15, ty = t >> 4;
  int n0 = blockIdx.x * 64, m0 = blockIdx.y * 64;
  float acc[4][4] = {};
  for (int k0 = 0; k0 < 256; k0 += 16) {
#pragma unroll
    for (int l = 0; l < 4; l++) {
      int e = t + l*256;
      int kk = e & 15, q = e >> 4;
      As[kk][q] = Ym[(size_t)(m0+q)*256 + k0+kk];
      Bs[kk][q] = recont[(size_t)(n0+q)*256 + k0+kk];
    }
    __syncthreads();
#pragma unroll
    for (int kk = 0; kk < 16; kk++) {
      float4 b4 = make_float4(Bs[kk][tx*4+0], Bs[kk][tx*4+1], Bs[kk][tx*4+2], Bs[kk][tx*4+3]);
      fma16(acc, As[kk][ty*4+0], As[kk][ty*4+1], As[kk][ty*4+2], As[kk][ty*4+3], b4);
    }
    __syncthreads();
  }
  float scale = sqrtf(cnrm[2+b]);
#pragma unroll
  for (int i = 0; i < 4; i++) {
    int r = m0 + ty*4 + i;
    float sm = smean[r];
    float4 o = make_float4(acc[i][0]*scale + sm, acc[i][1]*scale + sm,
                           acc[i][2]*scale + sm, acc[i][3]*scale + sm);
    *(float4*)&out[(size_t)r*N_ + n0 + tx*4] = o;
  }
}

extern "C" void kernel_launch(void* const* d_in, const int* in_sizes, int n_in,
                              void* d_out, int out_size, void* d_ws, size_t ws_size,
                              hipStream_t stream) {
  const float* content = (const float*)d_in[0];
  const float* style   = (const float*)d_in[1];
  float* out = (float*)d_out;

  // workspace layout (floats); total ~102 MiB
  float* F = (float*)d_ws;
  float* means  = F + 0;         // 4*256
  float* cnrm   = F + 1024;      // 4
  float* Y      = F + 264192;    // NS buffers, 256KB each region of 4 matrices
  float* Z      = F + 526336;
  float* Y2     = F + 788480;    // free after NS (NS_ITERS=6 even -> results in Y,Z)
  float* Z2     = F + 1050624;
  float* T      = F + 1312768;
  float* nc     = F + 1574912;   // 2*CN fp32 (dead after split(1))
  float* ns     = F + 3672064;   // 2*CN fp32 (dead after split(1))
  float* nstslot= F + 5769216;   // 2*CN floats = 4 fp16 plane slots (nsT h/l, ncT h/l)
  float* recont = F + 7866368;   // 2*CN fp32, written per batch at recon(b)
  float* ssq    = F + 9963520;   // 2*4096
  float* rnorm  = F + 9971712;   // 2*4096
  int*   idx    = (int*)(F + 9979904); // 2*4096
  float* Hx     = F + 9988096;   // 4096*4096 (16.7M floats)

  // cov-phase aliases inside Hx (dead until k_gram at step 8):
  //  - covsp: 4 m x 2 planes x CN ushorts = 8.39M ushorts = 4.19M floats (16.8 MB)
  //  - covp : KSPLIT(16) x 4 x 65536 = 4.19M floats; both consumed by covred before NS.
  unsigned short* covsp = (unsigned short*)Hx;
  float* covp = Hx + 2*(size_t)CN*2;   // = Hx + 4194304 floats

  // per-batch fp16 planes (each CN ushorts = 2 MB): all 4 fit in nstslot — no aliasing
  // with Y2/recont needed (the old 6-plane bf16 scheme's alias hazards are gone).
  unsigned short* nsTh = (unsigned short*)nstslot;
  unsigned short* nsTl = (unsigned short*)nstslot + (size_t)CN;
  unsigned short* ncTh = (unsigned short*)nstslot + 2*(size_t)CN;
  unsigned short* ncTl = (unsigned short*)nstslot + 3*(size_t)CN;

  // 1-4. means, fp16-split, MFMA cov partials, trace, covred+nsinit
  k_mean<<<dim3(256,4), 256, 0, stream>>>(content, style, means);
  k_splitcov<<<dim3(1024,4), 256, 0, stream>>>(content, style, covsp);
  k_covmm<<<dim3(KSPLIT,4,4), 512, 0, stream>>>(covsp, covp);
  k_trace2<<<4, 256, 0, stream>>>(covp, means, cnrm);
  k_covred_init<<<dim3(256,4), 256, 0, stream>>>(covp, means, cnrm, Y, Z);
  // 5. NS iterations (6, even -> results land back in Y,Z; Y2/Z2/T free afterwards)
  float *Ya = Y, *Za = Z, *Yb = Y2, *Zb = Z2;
  for (int it = 0; it < NS_ITERS; it++) {
    k_nsA<<<dim3(64,4), 256, 0, stream>>>(Za, Ya, T);
    k_nsB<<<dim3(64,4,2), 256, 0, stream>>>(Ya, Za, T, Yb, Zb);
    float* tmp;
    tmp = Ya; Ya = Yb; Yb = tmp;
    tmp = Za; Za = Zb; Zb = tmp;
  }
  // 6. whitening
  k_whiten<<<dim3(64,4,4), 256, 0, stream>>>(content, style, Za, means, cnrm, nc, ns);
  // 7. patch norms
  k_ssq<<<dim3(16,2), 256, 0, stream>>>(ns, ssq);
  k_rnorm<<<dim3(16,2), 256, 0, stream>>>(ssq, rnorm);
  // 8. per batch: split -> MFMA gram + x-blur -> y-blur+argmax -> recon
  for (int b = 0; b < 2; b++) {
    k_split<<<dim3(128,8,2), 256, 0, stream>>>(nc + (size_t)b*CN, ns + (size_t)b*CN,
                                               ncTh, ncTl, nsTh, nsTl);
    k_gram<<<dim3(32,32), 512, 0, stream>>>(ncTh, ncTl, nsTh, nsTl, Hx);
    k_argmax<<<4096, 256, 0, stream>>>(Hx, rnorm, idx, b);
    k_recon<<<4096, 256, 0, stream>>>(nsTh, nsTl, idx + (size_t)b*N_,
                                      recont + (size_t)b*CN);
  }
  // 9. coloring
  k_color<<<dim3(64,4,2), 256, 0, stream>>>(Ya, recont, cnrm, means, out);
}